// Round 16
// baseline (404.469 us; speedup 1.0000x reference)
//
#include <hip/hip_runtime.h>
#include <hip/hip_bf16.h>

// NodeProcessor via MFMA. R16: (1) amdgpu_waves_per_eu(3,3) — R15 proved the
// waves-per-eu attr gates residency (19.4->28.4%) but HIP's (256,3) let the
// allocator over-constrain VGPR to 84 -> spills (+89MB WRITE). Exact (3,3)
// gives budget ~170 >= natural 128 -> 3 waves, no spills. (2) msg v-part
// stored PLANE-MAJOR (ch = 64 + p*32 + c): V-epilogue stores become 32B
// contiguous chunks instead of stride-3 2B scatter (the ~79MB RMW overhead
// visible since R12). Gather permutation adjusted; sums bit-identical.
// Rest identical to R14/R15 (node-sorted edges, CSR gather, B reg-dbuf).

#define NNODES 10000
#define NEDGES 160000
#define EB 128
#define FSTRD 65                    // fTd row stride in dwords (==1 mod 32)

typedef unsigned short u16;
typedef unsigned int u32;
typedef short short8 __attribute__((ext_vector_type(8)));
typedef float f32x4 __attribute__((ext_vector_type(4)));

__device__ __forceinline__ u16 f2b(float f) {  // RNE
  union { float f; u32 i; } v; v.f = f;
  u32 r = v.i + 0x7FFFu + ((v.i >> 16) & 1u);
  return (u16)(r >> 16);
}
__device__ __forceinline__ float lo_f(u32 d) {
  union { u32 i; float f; } v; v.i = d << 16; return v.f;
}
__device__ __forceinline__ float hi_f(u32 d) {
  union { u32 i; float f; } v; v.i = d & 0xFFFF0000u; return v.f;
}
__device__ __forceinline__ float qb(float f) {  // quantize to bf16 grid
  union { u32 i; float f; } v; v.i = ((u32)f2b(f)) << 16; return v.f;
}
__device__ __forceinline__ u32 pk2(float lo, float hi) {
  return __builtin_amdgcn_perm(__float_as_uint(hi), __float_as_uint(lo), 0x07060302u);
}
union frag_u { u32 w[4]; short8 s; };

#define INVF  0.02795084971874737f   // 1/sqrt(1280)
#define INV3  0.5773502691896258f    // 1/sqrt(3)
#define INV2  0.7071067811865476f    // 1/sqrt(2)

// ---- prep: pack weights (+ fused degree count; cnt pre-zeroed by memset) --
__global__ void prep_kernel(const float* __restrict__ W_ss, const float* __restrict__ W_vv_s,
                            const float* __restrict__ W_sv, const float* __restrict__ W_vs,
                            const float* __restrict__ W_vv_v,
                            u32* __restrict__ WSd, u32* __restrict__ WVd,
                            const int* __restrict__ eidx, int* __restrict__ cnt,
                            int do_count) {
  int t = blockIdx.x * 256 + threadIdx.x;
  if (do_count && t < NEDGES) atomicAdd(&cnt[eidx[t]], 1);
  if (t < 61440) {            // W_S dwords
    int d = t;
    int nt = d / 10240, r = d - nt * 10240;
    int kt = r >> 8, l = (r & 255) >> 2, jp = r & 3;
    int n = nt * 16 + (l & 15);
    int k0 = kt * 32 + ((l >> 4) << 3) + jp * 2;
    float f0, f1;
    f0 = (k0     < 1024) ? W_ss[k0 * 96 + n] * INVF       : W_vv_s[(k0 - 1024) * 96 + n] * (INVF * INV3);
    f1 = (k0 + 1 < 1024) ? W_ss[(k0 + 1) * 96 + n] * INVF : W_vv_s[(k0 - 1023) * 96 + n] * (INVF * INV3);
    WSd[d] = (u32)f2b(f0) | ((u32)f2b(f1) << 16);
  } else if (t < 81920) {     // W_V dwords
    int d = t - 61440;
    int nt = d / 10240, r = d - nt * 10240;
    int kt = r >> 8, l = (r & 255) >> 2, jp = r & 3;
    int n = nt * 16 + (l & 15);
    int k0 = kt * 32 + ((l >> 4) << 3) + jp * 2;
    float f[2];
#pragma unroll
    for (int jj = 0; jj < 2; jj++) {
      int k = k0 + jj;
      if (k < 512)       f[jj] = W_sv[k * 32 + n] * INVF;
      else if (k < 1024) f[jj] = W_vs[(k - 512) * 32 + n] * INVF;
      else               f[jj] = W_vv_v[(k - 1024) * 32 + n] * (INVF * INV2);
    }
    WVd[d] = (u32)f2b(f[0]) | ((u32)f2b(f[1]) << 16);
  }
}

__global__ void scan_kernel(const int* __restrict__ cnt, int* __restrict__ off,
                            int* __restrict__ cursor) {
  __shared__ int part[1024];
  int t = threadIdx.x;
  int local[10]; int s = 0;
  if (t < 1000) {
#pragma unroll
    for (int i = 0; i < 10; i++) { local[i] = cnt[t * 10 + i]; s += local[i]; }
  }
  part[t] = s; __syncthreads();
  for (int d = 1; d < 1024; d <<= 1) {
    int v = (t >= d) ? part[t - d] : 0; __syncthreads();
    part[t] += v; __syncthreads();
  }
  if (t < 1000) {
    int ex = (t == 0) ? 0 : part[t - 1];
#pragma unroll
    for (int i = 0; i < 10; i++) { off[t * 10 + i] = ex; cursor[t * 10 + i] = ex; ex += local[i]; }
  }
  if (t == 0) off[10000] = NEDGES;
}

__global__ void fill_kernel(const int* __restrict__ eidx, int* __restrict__ cursor,
                            int* __restrict__ elist) {
  int t = blockIdx.x * 256 + threadIdx.x;
  if (t < NEDGES) {
    int slot = atomicAdd(&cursor[eidx[t]], 1);
    elist[slot] = t;
  }
}

// ---- edge kernel (processes SLOT order when use_msg) ---------------------
__global__ __launch_bounds__(256)
__attribute__((amdgpu_waves_per_eu(3, 3)))
void edge_kernel(
    const float* __restrict__ x, const float* __restrict__ ea,
    const int* __restrict__ eidx, const int* __restrict__ elist,
    const u16* __restrict__ WSp, const u16* __restrict__ WVp,
    float* __restrict__ s_n, float* __restrict__ v_n,
    u16* __restrict__ msg16, int use_msg) {
  __shared__ int idxL[EB];
  __shared__ int eoL[EB];
  __shared__ u32 fTd[160 * FSTRD];  // [j][ep]: lo=edge ep, hi=edge ep+64 (x only)
  const int tid = threadIdx.x;
  const int eb = blockIdx.x * EB;

  if (tid < EB) {
    int eo = use_msg ? elist[eb + tid] : (eb + tid);
    eoL[tid] = eo;
    idxL[tid] = eidx[eo];
  }
  __syncthreads();
#pragma unroll 1
  for (int t = tid; t < 64 * 160; t += 256) {
    int ep2 = t / 160, j = t - ep2 * 160;
    float vlo = x[(size_t)idxL[ep2] * 160 + j];
    float vhi = x[(size_t)idxL[ep2 + 64] * 160 + j];
    fTd[j * FSTRD + ep2] = (u32)f2b(vlo) | ((u32)f2b(vhi) << 16);
  }
  __syncthreads();

  const int wv = tid >> 6, lane = tid & 63;
  const int ln = lane & 15, quad = lane >> 4;
  const int ep = wv * 16 + ln;
  const int qh = quad >> 1, bb = (quad & 1) * 8;

  // s2/v2 hoists: straight from global (this lane's 2 edges), bf16-quantized
  const float* eaL = ea + (size_t)eoL[ep] * 40;
  const float* eaH = ea + (size_t)eoL[ep + 64] * 40;
  float s2l[8], s2h[8], v2l[24], v2h[24];
  {
    float4 a0 = *(const float4*)(eaL + bb), a1 = *(const float4*)(eaL + bb + 4);
    float4 b0 = *(const float4*)(eaH + bb), b1 = *(const float4*)(eaH + bb + 4);
    s2l[0]=qb(a0.x); s2l[1]=qb(a0.y); s2l[2]=qb(a0.z); s2l[3]=qb(a0.w);
    s2l[4]=qb(a1.x); s2l[5]=qb(a1.y); s2l[6]=qb(a1.z); s2l[7]=qb(a1.w);
    s2h[0]=qb(b0.x); s2h[1]=qb(b0.y); s2h[2]=qb(b0.z); s2h[3]=qb(b0.w);
    s2h[4]=qb(b1.x); s2h[5]=qb(b1.y); s2h[6]=qb(b1.z); s2h[7]=qb(b1.w);
#pragma unroll
    for (int i = 0; i < 6; i++) {
      float4 va = *(const float4*)(eaL + 16 + 4 * i);
      float4 vb = *(const float4*)(eaH + 16 + 4 * i);
      v2l[4*i+0]=qb(va.x); v2l[4*i+1]=qb(va.y); v2l[4*i+2]=qb(va.z); v2l[4*i+3]=qb(va.w);
      v2h[4*i+0]=qb(vb.x); v2h[4*i+1]=qb(vb.y); v2h[4*i+2]=qb(vb.z); v2h[4*i+3]=qb(vb.w);
    }
  }

  const u16* WS_l = WSp + (size_t)lane * 8;
  const u16* WV_l = WVp + (size_t)lane * 8;

#define LOAD_BS(B, ktv) { _Pragma("unroll") \
  for (int nt = 0; nt < 6; nt++) B[nt].s = *(const short8*)(WS_l + (size_t)(ktv) * 512 + nt * 20480); }
#define LOAD_BV(C, ktv) { _Pragma("unroll") \
  for (int nt = 0; nt < 2; nt++) C[nt].s = *(const short8*)(WV_l + (size_t)(ktv) * 512 + nt * 20480); }
#define MFMA_S(Al, Ah, B) { _Pragma("unroll") \
  for (int nt = 0; nt < 6; nt++) { \
    aS[0][nt] = __builtin_amdgcn_mfma_f32_16x16x32_bf16(Al.s, B[nt].s, aS[0][nt], 0, 0, 0); \
    aS[1][nt] = __builtin_amdgcn_mfma_f32_16x16x32_bf16(Ah.s, B[nt].s, aS[1][nt], 0, 0, 0); } }
#define MFMA_V(Al, Ah, C, p) { \
    aV[0][p][0] = __builtin_amdgcn_mfma_f32_16x16x32_bf16(Al.s, C[0].s, aV[0][p][0], 0, 0, 0); \
    aV[0][p][1] = __builtin_amdgcn_mfma_f32_16x16x32_bf16(Al.s, C[1].s, aV[0][p][1], 0, 0, 0); \
    aV[1][p][0] = __builtin_amdgcn_mfma_f32_16x16x32_bf16(Ah.s, C[0].s, aV[1][p][0], 0, 0, 0); \
    aV[1][p][1] = __builtin_amdgcn_mfma_f32_16x16x32_bf16(Ah.s, C[1].s, aV[1][p][1], 0, 0, 0); }

  // ================= S phase =================
  f32x4 aS[2][6];
#pragma unroll
  for (int t = 0; t < 2; t++)
#pragma unroll
    for (int i = 0; i < 6; i++) aS[t][i] = (f32x4){0.f, 0.f, 0.f, 0.f};

  frag_u B0[6], B1[6];
  LOAD_BS(B0, 0);

#pragma unroll 1
  for (int c = 0; c < 16; c++) {      // region ss: kt 0..31
    int kt = 2 * c;
    u32 dA = fTd[(2 * kt + qh) * FSTRD + ep];
    u32 dB = fTd[(2 * kt + 2 + qh) * FSTRD + ep];
    LOAD_BS(B1, kt + 1);
    {
      frag_u Al, Ah;
      float slo = lo_f(dA), shi = hi_f(dA);
#pragma unroll
      for (int jp = 0; jp < 4; jp++) {
        Al.w[jp] = pk2(slo * s2l[2 * jp], slo * s2l[2 * jp + 1]);
        Ah.w[jp] = pk2(shi * s2h[2 * jp], shi * s2h[2 * jp + 1]);
      }
      MFMA_S(Al, Ah, B0);
    }
    LOAD_BS(B0, kt + 2);
    {
      frag_u Al, Ah;
      float slo = lo_f(dB), shi = hi_f(dB);
#pragma unroll
      for (int jp = 0; jp < 4; jp++) {
        Al.w[jp] = pk2(slo * s2l[2 * jp], slo * s2l[2 * jp + 1]);
        Ah.w[jp] = pk2(shi * s2h[2 * jp], shi * s2h[2 * jp + 1]);
      }
      MFMA_S(Al, Ah, B1);
    }
  }
#pragma unroll 1
  for (int c = 0; c < 4; c++) {       // region dot3: kt 32..39
    int kt = 32 + 2 * c;
    int r0 = (64 + (4 * (kt - 32) + quad) * 3) * FSTRD + ep;
    int r1 = r0 + 12 * FSTRD;
    u32 d0 = fTd[r0], d1 = fTd[r0 + FSTRD], d2 = fTd[r0 + 2 * FSTRD];
    u32 e0 = fTd[r1], e1 = fTd[r1 + FSTRD], e2 = fTd[r1 + 2 * FSTRD];
    LOAD_BS(B1, kt + 1);
    {
      frag_u Al, Ah;
      float x0 = lo_f(d0), x1 = lo_f(d1), x2 = lo_f(d2);
      float y0 = hi_f(d0), y1 = hi_f(d1), y2 = hi_f(d2);
#pragma unroll
      for (int jp = 0; jp < 4; jp++) {
        int j0 = 6 * jp, j1 = 6 * jp + 3;
        Al.w[jp] = pk2(x0*v2l[j0] + x1*v2l[j0+1] + x2*v2l[j0+2],
                       x0*v2l[j1] + x1*v2l[j1+1] + x2*v2l[j1+2]);
        Ah.w[jp] = pk2(y0*v2h[j0] + y1*v2h[j0+1] + y2*v2h[j0+2],
                       y0*v2h[j1] + y1*v2h[j1+1] + y2*v2h[j1+2]);
      }
      MFMA_S(Al, Ah, B0);
    }
    LOAD_BS(B0, kt + 2);
    {
      frag_u Al, Ah;
      float x0 = lo_f(e0), x1 = lo_f(e1), x2 = lo_f(e2);
      float y0 = hi_f(e0), y1 = hi_f(e1), y2 = hi_f(e2);
#pragma unroll
      for (int jp = 0; jp < 4; jp++) {
        int j0 = 6 * jp, j1 = 6 * jp + 3;
        Al.w[jp] = pk2(x0*v2l[j0] + x1*v2l[j0+1] + x2*v2l[j0+2],
                       x0*v2l[j1] + x1*v2l[j1+1] + x2*v2l[j1+2]);
        Ah.w[jp] = pk2(y0*v2h[j0] + y1*v2h[j0+1] + y2*v2h[j0+2],
                       y0*v2h[j1] + y1*v2h[j1+1] + y2*v2h[j1+2]);
      }
      MFMA_S(Al, Ah, B1);
    }
  }

  frag_u C0[2], C1[2];
  LOAD_BV(C0, 32);

  // S epilogue: silu -> msg store (or atomic fallback); gates -> regs
  float gateR[16];
#pragma unroll
  for (int t = 0; t < 2; t++) {
#pragma unroll
    for (int r = 0; r < 4; r++) {
      int er = wv * 16 + quad * 4 + r + t * 64;
      int nid = idxL[er];
#pragma unroll
      for (int nt = 0; nt < 6; nt++) {
        float v = aS[t][nt][r];
        float sg = 1.f / (1.f + __expf(-v));
        if (nt < 4) {
          if (use_msg) msg16[(size_t)(eb + er) * 160 + nt * 16 + ln] = f2b(v * sg);
          else         atomicAdd(&s_n[nid * 64 + nt * 16 + ln], v * sg);
        } else gateR[t * 8 + (nt - 4) * 4 + r] = sg;
      }
    }
  }

  // ================= V phase =================
  f32x4 aV[2][3][2];
#pragma unroll
  for (int t = 0; t < 2; t++)
#pragma unroll
    for (int p = 0; p < 3; p++)
#pragma unroll
      for (int nt = 0; nt < 2; nt++) aV[t][p][nt] = (f32x4){0.f, 0.f, 0.f, 0.f};

#pragma unroll 1
  for (int c = 0; c < 4; c++) {       // region cross: kt 32..39
    int kt = 32 + 2 * c;
    int r0 = (64 + (4 * (kt - 32) + quad) * 3) * FSTRD + ep;
    int r1 = r0 + 12 * FSTRD;
    u32 d0 = fTd[r0], d1 = fTd[r0 + FSTRD], d2 = fTd[r0 + 2 * FSTRD];
    u32 e0 = fTd[r1], e1 = fTd[r1 + FSTRD], e2 = fTd[r1 + 2 * FSTRD];
    LOAD_BV(C1, kt + 1);
    {
      float wl[3] = { lo_f(d0), lo_f(d1), lo_f(d2) };
      float wh[3] = { hi_f(d0), hi_f(d1), hi_f(d2) };
#pragma unroll
      for (int p = 0; p < 3; p++) {
        const int p1 = (p + 1) % 3, p2 = (p + 2) % 3;
        frag_u Al, Ah;
#pragma unroll
        for (int jp = 0; jp < 4; jp++) {
          int j0 = 6 * jp, j1 = 6 * jp + 3;
          Al.w[jp] = pk2(wl[p1]*v2l[j0+p2] - wl[p2]*v2l[j0+p1],
                         wl[p1]*v2l[j1+p2] - wl[p2]*v2l[j1+p1]);
          Ah.w[jp] = pk2(wh[p1]*v2h[j0+p2] - wh[p2]*v2h[j0+p1],
                         wh[p1]*v2h[j1+p2] - wh[p2]*v2h[j1+p1]);
        }
        MFMA_V(Al, Ah, C0, p);
      }
    }
    LOAD_BV(C0, (c < 3) ? (kt + 2) : 0);
    {
      float wl[3] = { lo_f(e0), lo_f(e1), lo_f(e2) };
      float wh[3] = { hi_f(e0), hi_f(e1), hi_f(e2) };
#pragma unroll
      for (int p = 0; p < 3; p++) {
        const int p1 = (p + 1) % 3, p2 = (p + 2) % 3;
        frag_u Al, Ah;
#pragma unroll
        for (int jp = 0; jp < 4; jp++) {
          int j0 = 6 * jp, j1 = 6 * jp + 3;
          Al.w[jp] = pk2(wl[p1]*v2l[j0+p2] - wl[p2]*v2l[j0+p1],
                         wl[p1]*v2l[j1+p2] - wl[p2]*v2l[j1+p1]);
          Ah.w[jp] = pk2(wh[p1]*v2h[j0+p2] - wh[p2]*v2h[j0+p1],
                         wh[p1]*v2h[j1+p2] - wh[p2]*v2h[j1+p1]);
        }
        MFMA_V(Al, Ah, C1, p);
      }
    }
  }
#pragma unroll 1
  for (int c = 0; c < 8; c++) {       // region sv: kt 0..15
    int kt = 2 * c;
    u32 dA = fTd[(4 * kt + quad) * FSTRD + ep];
    u32 dB = fTd[(4 * kt + 4 + quad) * FSTRD + ep];
    LOAD_BV(C1, kt + 1);
    {
      float slo = lo_f(dA), shi = hi_f(dA);
#pragma unroll
      for (int p = 0; p < 3; p++) {
        frag_u Al, Ah;
#pragma unroll
        for (int jp = 0; jp < 4; jp++) {
          Al.w[jp] = pk2(slo * v2l[(2*jp)*3 + p], slo * v2l[(2*jp+1)*3 + p]);
          Ah.w[jp] = pk2(shi * v2h[(2*jp)*3 + p], shi * v2h[(2*jp+1)*3 + p]);
        }
        MFMA_V(Al, Ah, C0, p);
      }
    }
    LOAD_BV(C0, kt + 2);
    {
      float slo = lo_f(dB), shi = hi_f(dB);
#pragma unroll
      for (int p = 0; p < 3; p++) {
        frag_u Al, Ah;
#pragma unroll
        for (int jp = 0; jp < 4; jp++) {
          Al.w[jp] = pk2(slo * v2l[(2*jp)*3 + p], slo * v2l[(2*jp+1)*3 + p]);
          Ah.w[jp] = pk2(shi * v2h[(2*jp)*3 + p], shi * v2h[(2*jp+1)*3 + p]);
        }
        MFMA_V(Al, Ah, C1, p);
      }
    }
  }
#pragma unroll 1
  for (int c = 0; c < 8; c++) {       // region vs: kt 16..31
    int kt = 16 + 2 * c;
    int r0 = (64 + (2 * (kt - 16) + qh) * 3) * FSTRD + ep;
    int r1 = r0 + 6 * FSTRD;
    u32 d0 = fTd[r0], d1 = fTd[r0 + FSTRD], d2 = fTd[r0 + 2 * FSTRD];
    u32 e0 = fTd[r1], e1 = fTd[r1 + FSTRD], e2 = fTd[r1 + 2 * FSTRD];
    LOAD_BV(C1, kt + 1);
    {
      float vl[3] = { lo_f(d0), lo_f(d1), lo_f(d2) };
      float vh[3] = { hi_f(d0), hi_f(d1), hi_f(d2) };
#pragma unroll
      for (int p = 0; p < 3; p++) {
        frag_u Al, Ah;
#pragma unroll
        for (int jp = 0; jp < 4; jp++) {
          Al.w[jp] = pk2(vl[p] * s2l[2*jp], vl[p] * s2l[2*jp+1]);
          Ah.w[jp] = pk2(vh[p] * s2h[2*jp], vh[p] * s2h[2*jp+1]);
        }
        MFMA_V(Al, Ah, C0, p);
      }
    }
    LOAD_BV(C0, (c < 7) ? (kt + 2) : 0);
    {
      float vl[3] = { lo_f(e0), lo_f(e1), lo_f(e2) };
      float vh[3] = { hi_f(e0), hi_f(e1), hi_f(e2) };
#pragma unroll
      for (int p = 0; p < 3; p++) {
        frag_u Al, Ah;
#pragma unroll
        for (int jp = 0; jp < 4; jp++) {
          Al.w[jp] = pk2(vl[p] * s2l[2*jp], vl[p] * s2l[2*jp+1]);
          Ah.w[jp] = pk2(vh[p] * s2h[2*jp], vh[p] * s2h[2*jp+1]);
        }
        MFMA_V(Al, Ah, C1, p);
      }
    }
  }

  // V epilogue: gate + msg store, PLANE-MAJOR v channels: ch = 64 + p*32 + c
  // -> per-instruction stores are 16 lanes x 2B contiguous (32B chunks)
#pragma unroll
  for (int t = 0; t < 2; t++) {
#pragma unroll
    for (int r = 0; r < 4; r++) {
      int er = wv * 16 + quad * 4 + r + t * 64;
      int nid = idxL[er];
#pragma unroll
      for (int nt = 0; nt < 2; nt++) {
        int c = nt * 16 + ln;
        float g = gateR[t * 8 + nt * 4 + r];
#pragma unroll
        for (int p = 0; p < 3; p++) {
          float val = aV[t][p][nt][r] * g;
          if (use_msg) msg16[(size_t)(eb + er) * 160 + 64 + p * 32 + c] = f2b(val);
          else         atomicAdd(&v_n[nid * 96 + c * 3 + p], val);
        }
      }
    }
  }
}

// ---- gather: one wave per node; msg rows contiguous per node -------------
// dword d of row: d<32 -> s ch 2d,2d+1; d=32..79 -> v plane-major:
// p=(d-32)/16, c=2*((d-32)&15) ... lane<64 reads d=lane; lane<16 reads 64+lane.
__global__ __launch_bounds__(256) void gather_kernel(
    const int* __restrict__ off, const u32* __restrict__ msg,
    float* __restrict__ s_n, float* __restrict__ v_n) {
  int tid = threadIdx.x;
  int n = blockIdx.x * 4 + (tid >> 6);
  int lane = tid & 63;
  int beg = off[n], end = off[n + 1];
  float a0 = 0.f, a1 = 0.f, b0 = 0.f, b1 = 0.f;
#pragma unroll 2
  for (int k = beg; k < end; k++) {
    u32 w0 = msg[(size_t)k * 80 + lane];
    a0 += lo_f(w0); a1 += hi_f(w0);
    if (lane < 16) {
      u32 w1 = msg[(size_t)k * 80 + 64 + lane];
      b0 += lo_f(w1); b1 += hi_f(w1);
    }
  }
  if (lane < 32) {
    s_n[n * 64 + 2 * lane] = a0; s_n[n * 64 + 2 * lane + 1] = a1;
  } else if (lane < 48) {            // p=0, c=2*(lane-32)
    int c = 2 * (lane - 32);
    v_n[n * 96 + c * 3] = a0; v_n[n * 96 + (c + 1) * 3] = a1;
  } else {                           // p=1, c=2*(lane-48)
    int c = 2 * (lane - 48);
    v_n[n * 96 + c * 3 + 1] = a0; v_n[n * 96 + (c + 1) * 3 + 1] = a1;
  }
  if (lane < 16) {                   // p=2, c=2*lane
    int c = 2 * lane;
    v_n[n * 96 + c * 3 + 2] = b0; v_n[n * 96 + (c + 1) * 3 + 2] = b1;
  }
}

// ---- BN stats ------------------------------------------------------------
__global__ void stats_kernel(const float* __restrict__ s_n, const float* __restrict__ v_n,
                             float* __restrict__ stats) {
  int b = blockIdx.x, tid = threadIdx.x;
  int r0 = b * 50;
  int c = tid & 63, rg = tid >> 6;
  float s = 0.f, sq = 0.f;
  for (int r = r0 + rg; r < r0 + 50; r += 4) {
    float v = s_n[r * 64 + c];
    s += v; sq += v * v;
  }
  atomicAdd(&stats[c], s);
  atomicAdd(&stats[64 + c], sq);
  int c2 = tid & 31, rg2 = tid >> 5;
  float vn = 0.f;
  for (int r = r0 + rg2; r < r0 + 50; r += 8) {
    const float* vp = &v_n[r * 96 + c2 * 3];
    vn += vp[0] * vp[0] + vp[1] * vp[1] + vp[2] * vp[2];
  }
  atomicAdd(&stats[128 + c2], vn);
}

// ---- finalize ------------------------------------------------------------
__global__ void finalize_kernel(const float* __restrict__ s_n, const float* __restrict__ v_n,
                                const float* __restrict__ stats,
                                const float* __restrict__ x,
                                const float* __restrict__ bw_s, const float* __restrict__ bb_s,
                                const float* __restrict__ bw_v,
                                float* __restrict__ out) {
  int t = blockIdx.x * 256 + threadIdx.x;
  if (t >= NNODES * 160) return;
  int n = t / 160, j = t - n * 160;
  float xv = x[t];
  float r;
  if (j < 64) {
    float mu  = stats[j] * (1.f / NNODES);
    float var = stats[64 + j] * (1.f / NNODES) - mu * mu;
    var = fmaxf(var, 0.f);
    float v = s_n[n * 64 + j];
    r = (v - mu) * rsqrtf(var + 1e-5f) * bw_s[j] + bb_s[j];
  } else {
    int qq = j - 64;
    int c = qq / 3;
    float vn = stats[128 + c] * (1.f / (3.f * NNODES));
    float v = v_n[n * 96 + qq];
    r = v * rsqrtf(vn + 1e-5f) * bw_v[c];
  }
  out[t] = r + xv;
}

extern "C" void kernel_launch(void* const* d_in, const int* in_sizes, int n_in,
                              void* d_out, int out_size, void* d_ws, size_t ws_size,
                              hipStream_t stream) {
  const float* x      = (const float*)d_in[0];
  const float* ea     = (const float*)d_in[1];
  const float* W_ss   = (const float*)d_in[2];
  const float* W_vv_s = (const float*)d_in[3];
  const float* W_sv   = (const float*)d_in[4];
  const float* W_vs   = (const float*)d_in[5];
  const float* W_vv_v = (const float*)d_in[6];
  const float* bw_s   = (const float*)d_in[7];
  const float* bb_s   = (const float*)d_in[8];
  const float* bw_v   = (const float*)d_in[9];
  const int* eidx     = (const int*)d_in[10];
  float* out = (float*)d_out;

  float* ws    = (float*)d_ws;
  u16* WSp     = (u16*)d_ws;              // 122880 u16
  u16* WVp     = WSp + 122880;            // 40960 u16
  float* s_n   = ws + 81920;              // 640000
  float* v_n   = s_n + 640000;            // 960000
  float* stats = v_n + 960000;            // 160  (at 1681920)
  int* cnt     = (int*)(ws + 1682080);    // 10000 (contiguous after stats)
  int* off     = (int*)(ws + 1692080);    // 10001 (pad to 10004)
  int* cursor  = (int*)(ws + 1702084);    // 10000
  int* elist   = (int*)(ws + 1712084);    // 160000
  u32* msg     = (u32*)(ws + 1872084);    // 12,800,000 dwords = msg[e][160] bf16
  // total = 14,672,084 floats = 58,688,336 bytes

  int use_msg = (ws_size >= 58688336ULL) ? 1 : 0;

  if (use_msg) {
    // stats (160 f) and cnt (10000 i32) are adjacent: one memset covers both
    hipMemsetAsync(stats, 0, (160 + NNODES) * sizeof(float), stream);
    prep_kernel<<<625, 256, 0, stream>>>(W_ss, W_vv_s, W_sv, W_vs, W_vv_v,
                                         (u32*)WSp, (u32*)WVp, eidx, cnt, 1);
    scan_kernel<<<1, 1024, 0, stream>>>(cnt, off, cursor);
    fill_kernel<<<625, 256, 0, stream>>>(eidx, cursor, elist);
  } else {
    hipMemsetAsync(s_n, 0, 1600160 * sizeof(float), stream);
    prep_kernel<<<625, 256, 0, stream>>>(W_ss, W_vv_s, W_sv, W_vs, W_vv_v,
                                         (u32*)WSp, (u32*)WVp, eidx, cnt, 0);
  }
  edge_kernel<<<NEDGES / EB, 256, 0, stream>>>(x, ea, eidx, elist, WSp, WVp,
                                               s_n, v_n, (u16*)msg, use_msg);
  if (use_msg)
    gather_kernel<<<2500, 256, 0, stream>>>(off, msg, s_n, v_n);
  stats_kernel<<<200, 256, 0, stream>>>(s_n, v_n, stats);
  finalize_kernel<<<(NNODES * 160 + 255) / 256, 256, 0, stream>>>(
      s_n, v_n, stats, x, bw_s, bb_s, bw_v, out);
}

// Round 17
// 356.259 us; speedup vs baseline: 1.1353x; 1.1353x over previous
//
#include <hip/hip_runtime.h>
#include <hip/hip_bf16.h>

// NodeProcessor via MFMA. R17 = R14 config (launch_bounds(256,2), VGPR~128,
// NO spills) + plane-major msg v-part (ch = 64+p*32+c -> 32B-contiguous
// stores, kills ~79MB stride-3 RMW write inflation measured R12-R14).
// R15/R16 lesson: unified VGPR+AGPR total ~224/wave hard-caps residency at
// 2 waves/SIMD; any forced 3-wave budget (170) spills ~50 regs and loses
// more than it gains. Occupancy 19.4% is accepted; attack traffic instead.

#define NNODES 10000
#define NEDGES 160000
#define EB 128
#define FSTRD 65                    // fTd row stride in dwords (==1 mod 32)

typedef unsigned short u16;
typedef unsigned int u32;
typedef short short8 __attribute__((ext_vector_type(8)));
typedef float f32x4 __attribute__((ext_vector_type(4)));

__device__ __forceinline__ u16 f2b(float f) {  // RNE
  union { float f; u32 i; } v; v.f = f;
  u32 r = v.i + 0x7FFFu + ((v.i >> 16) & 1u);
  return (u16)(r >> 16);
}
__device__ __forceinline__ float lo_f(u32 d) {
  union { u32 i; float f; } v; v.i = d << 16; return v.f;
}
__device__ __forceinline__ float hi_f(u32 d) {
  union { u32 i; float f; } v; v.i = d & 0xFFFF0000u; return v.f;
}
__device__ __forceinline__ float qb(float f) {  // quantize to bf16 grid
  union { u32 i; float f; } v; v.i = ((u32)f2b(f)) << 16; return v.f;
}
__device__ __forceinline__ u32 pk2(float lo, float hi) {
  return __builtin_amdgcn_perm(__float_as_uint(hi), __float_as_uint(lo), 0x07060302u);
}
union frag_u { u32 w[4]; short8 s; };

#define INVF  0.02795084971874737f   // 1/sqrt(1280)
#define INV3  0.5773502691896258f    // 1/sqrt(3)
#define INV2  0.7071067811865476f    // 1/sqrt(2)

// ---- prep: pack weights (+ fused degree count; cnt pre-zeroed by memset) --
__global__ void prep_kernel(const float* __restrict__ W_ss, const float* __restrict__ W_vv_s,
                            const float* __restrict__ W_sv, const float* __restrict__ W_vs,
                            const float* __restrict__ W_vv_v,
                            u32* __restrict__ WSd, u32* __restrict__ WVd,
                            const int* __restrict__ eidx, int* __restrict__ cnt,
                            int do_count) {
  int t = blockIdx.x * 256 + threadIdx.x;
  if (do_count && t < NEDGES) atomicAdd(&cnt[eidx[t]], 1);
  if (t < 61440) {            // W_S dwords
    int d = t;
    int nt = d / 10240, r = d - nt * 10240;
    int kt = r >> 8, l = (r & 255) >> 2, jp = r & 3;
    int n = nt * 16 + (l & 15);
    int k0 = kt * 32 + ((l >> 4) << 3) + jp * 2;
    float f0, f1;
    f0 = (k0     < 1024) ? W_ss[k0 * 96 + n] * INVF       : W_vv_s[(k0 - 1024) * 96 + n] * (INVF * INV3);
    f1 = (k0 + 1 < 1024) ? W_ss[(k0 + 1) * 96 + n] * INVF : W_vv_s[(k0 - 1023) * 96 + n] * (INVF * INV3);
    WSd[d] = (u32)f2b(f0) | ((u32)f2b(f1) << 16);
  } else if (t < 81920) {     // W_V dwords
    int d = t - 61440;
    int nt = d / 10240, r = d - nt * 10240;
    int kt = r >> 8, l = (r & 255) >> 2, jp = r & 3;
    int n = nt * 16 + (l & 15);
    int k0 = kt * 32 + ((l >> 4) << 3) + jp * 2;
    float f[2];
#pragma unroll
    for (int jj = 0; jj < 2; jj++) {
      int k = k0 + jj;
      if (k < 512)       f[jj] = W_sv[k * 32 + n] * INVF;
      else if (k < 1024) f[jj] = W_vs[(k - 512) * 32 + n] * INVF;
      else               f[jj] = W_vv_v[(k - 1024) * 32 + n] * (INVF * INV2);
    }
    WVd[d] = (u32)f2b(f[0]) | ((u32)f2b(f[1]) << 16);
  }
}

__global__ void scan_kernel(const int* __restrict__ cnt, int* __restrict__ off,
                            int* __restrict__ cursor) {
  __shared__ int part[1024];
  int t = threadIdx.x;
  int local[10]; int s = 0;
  if (t < 1000) {
#pragma unroll
    for (int i = 0; i < 10; i++) { local[i] = cnt[t * 10 + i]; s += local[i]; }
  }
  part[t] = s; __syncthreads();
  for (int d = 1; d < 1024; d <<= 1) {
    int v = (t >= d) ? part[t - d] : 0; __syncthreads();
    part[t] += v; __syncthreads();
  }
  if (t < 1000) {
    int ex = (t == 0) ? 0 : part[t - 1];
#pragma unroll
    for (int i = 0; i < 10; i++) { off[t * 10 + i] = ex; cursor[t * 10 + i] = ex; ex += local[i]; }
  }
  if (t == 0) off[10000] = NEDGES;
}

__global__ void fill_kernel(const int* __restrict__ eidx, int* __restrict__ cursor,
                            int* __restrict__ elist) {
  int t = blockIdx.x * 256 + threadIdx.x;
  if (t < NEDGES) {
    int slot = atomicAdd(&cursor[eidx[t]], 1);
    elist[slot] = t;
  }
}

// ---- edge kernel (processes SLOT order when use_msg) ---------------------
__global__ __launch_bounds__(256, 2) void edge_kernel(
    const float* __restrict__ x, const float* __restrict__ ea,
    const int* __restrict__ eidx, const int* __restrict__ elist,
    const u16* __restrict__ WSp, const u16* __restrict__ WVp,
    float* __restrict__ s_n, float* __restrict__ v_n,
    u16* __restrict__ msg16, int use_msg) {
  __shared__ int idxL[EB];
  __shared__ int eoL[EB];
  __shared__ u32 fTd[160 * FSTRD];  // [j][ep]: lo=edge ep, hi=edge ep+64 (x only)
  const int tid = threadIdx.x;
  const int eb = blockIdx.x * EB;

  if (tid < EB) {
    int eo = use_msg ? elist[eb + tid] : (eb + tid);
    eoL[tid] = eo;
    idxL[tid] = eidx[eo];
  }
  __syncthreads();
#pragma unroll 1
  for (int t = tid; t < 64 * 160; t += 256) {
    int ep2 = t / 160, j = t - ep2 * 160;
    float vlo = x[(size_t)idxL[ep2] * 160 + j];
    float vhi = x[(size_t)idxL[ep2 + 64] * 160 + j];
    fTd[j * FSTRD + ep2] = (u32)f2b(vlo) | ((u32)f2b(vhi) << 16);
  }
  __syncthreads();

  const int wv = tid >> 6, lane = tid & 63;
  const int ln = lane & 15, quad = lane >> 4;
  const int ep = wv * 16 + ln;
  const int qh = quad >> 1, bb = (quad & 1) * 8;

  // s2/v2 hoists: straight from global (this lane's 2 edges), bf16-quantized
  const float* eaL = ea + (size_t)eoL[ep] * 40;
  const float* eaH = ea + (size_t)eoL[ep + 64] * 40;
  float s2l[8], s2h[8], v2l[24], v2h[24];
  {
    float4 a0 = *(const float4*)(eaL + bb), a1 = *(const float4*)(eaL + bb + 4);
    float4 b0 = *(const float4*)(eaH + bb), b1 = *(const float4*)(eaH + bb + 4);
    s2l[0]=qb(a0.x); s2l[1]=qb(a0.y); s2l[2]=qb(a0.z); s2l[3]=qb(a0.w);
    s2l[4]=qb(a1.x); s2l[5]=qb(a1.y); s2l[6]=qb(a1.z); s2l[7]=qb(a1.w);
    s2h[0]=qb(b0.x); s2h[1]=qb(b0.y); s2h[2]=qb(b0.z); s2h[3]=qb(b0.w);
    s2h[4]=qb(b1.x); s2h[5]=qb(b1.y); s2h[6]=qb(b1.z); s2h[7]=qb(b1.w);
#pragma unroll
    for (int i = 0; i < 6; i++) {
      float4 va = *(const float4*)(eaL + 16 + 4 * i);
      float4 vb = *(const float4*)(eaH + 16 + 4 * i);
      v2l[4*i+0]=qb(va.x); v2l[4*i+1]=qb(va.y); v2l[4*i+2]=qb(va.z); v2l[4*i+3]=qb(va.w);
      v2h[4*i+0]=qb(vb.x); v2h[4*i+1]=qb(vb.y); v2h[4*i+2]=qb(vb.z); v2h[4*i+3]=qb(vb.w);
    }
  }

  const u16* WS_l = WSp + (size_t)lane * 8;
  const u16* WV_l = WVp + (size_t)lane * 8;

#define LOAD_BS(B, ktv) { _Pragma("unroll") \
  for (int nt = 0; nt < 6; nt++) B[nt].s = *(const short8*)(WS_l + (size_t)(ktv) * 512 + nt * 20480); }
#define LOAD_BV(C, ktv) { _Pragma("unroll") \
  for (int nt = 0; nt < 2; nt++) C[nt].s = *(const short8*)(WV_l + (size_t)(ktv) * 512 + nt * 20480); }
#define MFMA_S(Al, Ah, B) { _Pragma("unroll") \
  for (int nt = 0; nt < 6; nt++) { \
    aS[0][nt] = __builtin_amdgcn_mfma_f32_16x16x32_bf16(Al.s, B[nt].s, aS[0][nt], 0, 0, 0); \
    aS[1][nt] = __builtin_amdgcn_mfma_f32_16x16x32_bf16(Ah.s, B[nt].s, aS[1][nt], 0, 0, 0); } }
#define MFMA_V(Al, Ah, C, p) { \
    aV[0][p][0] = __builtin_amdgcn_mfma_f32_16x16x32_bf16(Al.s, C[0].s, aV[0][p][0], 0, 0, 0); \
    aV[0][p][1] = __builtin_amdgcn_mfma_f32_16x16x32_bf16(Al.s, C[1].s, aV[0][p][1], 0, 0, 0); \
    aV[1][p][0] = __builtin_amdgcn_mfma_f32_16x16x32_bf16(Ah.s, C[0].s, aV[1][p][0], 0, 0, 0); \
    aV[1][p][1] = __builtin_amdgcn_mfma_f32_16x16x32_bf16(Ah.s, C[1].s, aV[1][p][1], 0, 0, 0); }

  // ================= S phase =================
  f32x4 aS[2][6];
#pragma unroll
  for (int t = 0; t < 2; t++)
#pragma unroll
    for (int i = 0; i < 6; i++) aS[t][i] = (f32x4){0.f, 0.f, 0.f, 0.f};

  frag_u B0[6], B1[6];
  LOAD_BS(B0, 0);

#pragma unroll 1
  for (int c = 0; c < 16; c++) {      // region ss: kt 0..31
    int kt = 2 * c;
    u32 dA = fTd[(2 * kt + qh) * FSTRD + ep];
    u32 dB = fTd[(2 * kt + 2 + qh) * FSTRD + ep];
    LOAD_BS(B1, kt + 1);
    {
      frag_u Al, Ah;
      float slo = lo_f(dA), shi = hi_f(dA);
#pragma unroll
      for (int jp = 0; jp < 4; jp++) {
        Al.w[jp] = pk2(slo * s2l[2 * jp], slo * s2l[2 * jp + 1]);
        Ah.w[jp] = pk2(shi * s2h[2 * jp], shi * s2h[2 * jp + 1]);
      }
      MFMA_S(Al, Ah, B0);
    }
    LOAD_BS(B0, kt + 2);
    {
      frag_u Al, Ah;
      float slo = lo_f(dB), shi = hi_f(dB);
#pragma unroll
      for (int jp = 0; jp < 4; jp++) {
        Al.w[jp] = pk2(slo * s2l[2 * jp], slo * s2l[2 * jp + 1]);
        Ah.w[jp] = pk2(shi * s2h[2 * jp], shi * s2h[2 * jp + 1]);
      }
      MFMA_S(Al, Ah, B1);
    }
  }
#pragma unroll 1
  for (int c = 0; c < 4; c++) {       // region dot3: kt 32..39
    int kt = 32 + 2 * c;
    int r0 = (64 + (4 * (kt - 32) + quad) * 3) * FSTRD + ep;
    int r1 = r0 + 12 * FSTRD;
    u32 d0 = fTd[r0], d1 = fTd[r0 + FSTRD], d2 = fTd[r0 + 2 * FSTRD];
    u32 e0 = fTd[r1], e1 = fTd[r1 + FSTRD], e2 = fTd[r1 + 2 * FSTRD];
    LOAD_BS(B1, kt + 1);
    {
      frag_u Al, Ah;
      float x0 = lo_f(d0), x1 = lo_f(d1), x2 = lo_f(d2);
      float y0 = hi_f(d0), y1 = hi_f(d1), y2 = hi_f(d2);
#pragma unroll
      for (int jp = 0; jp < 4; jp++) {
        int j0 = 6 * jp, j1 = 6 * jp + 3;
        Al.w[jp] = pk2(x0*v2l[j0] + x1*v2l[j0+1] + x2*v2l[j0+2],
                       x0*v2l[j1] + x1*v2l[j1+1] + x2*v2l[j1+2]);
        Ah.w[jp] = pk2(y0*v2h[j0] + y1*v2h[j0+1] + y2*v2h[j0+2],
                       y0*v2h[j1] + y1*v2h[j1+1] + y2*v2h[j1+2]);
      }
      MFMA_S(Al, Ah, B0);
    }
    LOAD_BS(B0, kt + 2);
    {
      frag_u Al, Ah;
      float x0 = lo_f(e0), x1 = lo_f(e1), x2 = lo_f(e2);
      float y0 = hi_f(e0), y1 = hi_f(e1), y2 = hi_f(e2);
#pragma unroll
      for (int jp = 0; jp < 4; jp++) {
        int j0 = 6 * jp, j1 = 6 * jp + 3;
        Al.w[jp] = pk2(x0*v2l[j0] + x1*v2l[j0+1] + x2*v2l[j0+2],
                       x0*v2l[j1] + x1*v2l[j1+1] + x2*v2l[j1+2]);
        Ah.w[jp] = pk2(y0*v2h[j0] + y1*v2h[j0+1] + y2*v2h[j0+2],
                       y0*v2h[j1] + y1*v2h[j1+1] + y2*v2h[j1+2]);
      }
      MFMA_S(Al, Ah, B1);
    }
  }

  frag_u C0[2], C1[2];
  LOAD_BV(C0, 32);

  // S epilogue: silu -> msg store (or atomic fallback); gates -> regs
  float gateR[16];
#pragma unroll
  for (int t = 0; t < 2; t++) {
#pragma unroll
    for (int r = 0; r < 4; r++) {
      int er = wv * 16 + quad * 4 + r + t * 64;
      int nid = idxL[er];
#pragma unroll
      for (int nt = 0; nt < 6; nt++) {
        float v = aS[t][nt][r];
        float sg = 1.f / (1.f + __expf(-v));
        if (nt < 4) {
          if (use_msg) msg16[(size_t)(eb + er) * 160 + nt * 16 + ln] = f2b(v * sg);
          else         atomicAdd(&s_n[nid * 64 + nt * 16 + ln], v * sg);
        } else gateR[t * 8 + (nt - 4) * 4 + r] = sg;
      }
    }
  }

  // ================= V phase =================
  f32x4 aV[2][3][2];
#pragma unroll
  for (int t = 0; t < 2; t++)
#pragma unroll
    for (int p = 0; p < 3; p++)
#pragma unroll
      for (int nt = 0; nt < 2; nt++) aV[t][p][nt] = (f32x4){0.f, 0.f, 0.f, 0.f};

#pragma unroll 1
  for (int c = 0; c < 4; c++) {       // region cross: kt 32..39
    int kt = 32 + 2 * c;
    int r0 = (64 + (4 * (kt - 32) + quad) * 3) * FSTRD + ep;
    int r1 = r0 + 12 * FSTRD;
    u32 d0 = fTd[r0], d1 = fTd[r0 + FSTRD], d2 = fTd[r0 + 2 * FSTRD];
    u32 e0 = fTd[r1], e1 = fTd[r1 + FSTRD], e2 = fTd[r1 + 2 * FSTRD];
    LOAD_BV(C1, kt + 1);
    {
      float wl[3] = { lo_f(d0), lo_f(d1), lo_f(d2) };
      float wh[3] = { hi_f(d0), hi_f(d1), hi_f(d2) };
#pragma unroll
      for (int p = 0; p < 3; p++) {
        const int p1 = (p + 1) % 3, p2 = (p + 2) % 3;
        frag_u Al, Ah;
#pragma unroll
        for (int jp = 0; jp < 4; jp++) {
          int j0 = 6 * jp, j1 = 6 * jp + 3;
          Al.w[jp] = pk2(wl[p1]*v2l[j0+p2] - wl[p2]*v2l[j0+p1],
                         wl[p1]*v2l[j1+p2] - wl[p2]*v2l[j1+p1]);
          Ah.w[jp] = pk2(wh[p1]*v2h[j0+p2] - wh[p2]*v2h[j0+p1],
                         wh[p1]*v2h[j1+p2] - wh[p2]*v2h[j1+p1]);
        }
        MFMA_V(Al, Ah, C0, p);
      }
    }
    LOAD_BV(C0, (c < 3) ? (kt + 2) : 0);
    {
      float wl[3] = { lo_f(e0), lo_f(e1), lo_f(e2) };
      float wh[3] = { hi_f(e0), hi_f(e1), hi_f(e2) };
#pragma unroll
      for (int p = 0; p < 3; p++) {
        const int p1 = (p + 1) % 3, p2 = (p + 2) % 3;
        frag_u Al, Ah;
#pragma unroll
        for (int jp = 0; jp < 4; jp++) {
          int j0 = 6 * jp, j1 = 6 * jp + 3;
          Al.w[jp] = pk2(wl[p1]*v2l[j0+p2] - wl[p2]*v2l[j0+p1],
                         wl[p1]*v2l[j1+p2] - wl[p2]*v2l[j1+p1]);
          Ah.w[jp] = pk2(wh[p1]*v2h[j0+p2] - wh[p2]*v2h[j0+p1],
                         wh[p1]*v2h[j1+p2] - wh[p2]*v2h[j1+p1]);
        }
        MFMA_V(Al, Ah, C1, p);
      }
    }
  }
#pragma unroll 1
  for (int c = 0; c < 8; c++) {       // region sv: kt 0..15
    int kt = 2 * c;
    u32 dA = fTd[(4 * kt + quad) * FSTRD + ep];
    u32 dB = fTd[(4 * kt + 4 + quad) * FSTRD + ep];
    LOAD_BV(C1, kt + 1);
    {
      float slo = lo_f(dA), shi = hi_f(dA);
#pragma unroll
      for (int p = 0; p < 3; p++) {
        frag_u Al, Ah;
#pragma unroll
        for (int jp = 0; jp < 4; jp++) {
          Al.w[jp] = pk2(slo * v2l[(2*jp)*3 + p], slo * v2l[(2*jp+1)*3 + p]);
          Ah.w[jp] = pk2(shi * v2h[(2*jp)*3 + p], shi * v2h[(2*jp+1)*3 + p]);
        }
        MFMA_V(Al, Ah, C0, p);
      }
    }
    LOAD_BV(C0, kt + 2);
    {
      float slo = lo_f(dB), shi = hi_f(dB);
#pragma unroll
      for (int p = 0; p < 3; p++) {
        frag_u Al, Ah;
#pragma unroll
        for (int jp = 0; jp < 4; jp++) {
          Al.w[jp] = pk2(slo * v2l[(2*jp)*3 + p], slo * v2l[(2*jp+1)*3 + p]);
          Ah.w[jp] = pk2(shi * v2h[(2*jp)*3 + p], shi * v2h[(2*jp+1)*3 + p]);
        }
        MFMA_V(Al, Ah, C1, p);
      }
    }
  }
#pragma unroll 1
  for (int c = 0; c < 8; c++) {       // region vs: kt 16..31
    int kt = 16 + 2 * c;
    int r0 = (64 + (2 * (kt - 16) + qh) * 3) * FSTRD + ep;
    int r1 = r0 + 6 * FSTRD;
    u32 d0 = fTd[r0], d1 = fTd[r0 + FSTRD], d2 = fTd[r0 + 2 * FSTRD];
    u32 e0 = fTd[r1], e1 = fTd[r1 + FSTRD], e2 = fTd[r1 + 2 * FSTRD];
    LOAD_BV(C1, kt + 1);
    {
      float vl[3] = { lo_f(d0), lo_f(d1), lo_f(d2) };
      float vh[3] = { hi_f(d0), hi_f(d1), hi_f(d2) };
#pragma unroll
      for (int p = 0; p < 3; p++) {
        frag_u Al, Ah;
#pragma unroll
        for (int jp = 0; jp < 4; jp++) {
          Al.w[jp] = pk2(vl[p] * s2l[2*jp], vl[p] * s2l[2*jp+1]);
          Ah.w[jp] = pk2(vh[p] * s2h[2*jp], vh[p] * s2h[2*jp+1]);
        }
        MFMA_V(Al, Ah, C0, p);
      }
    }
    LOAD_BV(C0, (c < 7) ? (kt + 2) : 0);
    {
      float vl[3] = { lo_f(e0), lo_f(e1), lo_f(e2) };
      float vh[3] = { hi_f(e0), hi_f(e1), hi_f(e2) };
#pragma unroll
      for (int p = 0; p < 3; p++) {
        frag_u Al, Ah;
#pragma unroll
        for (int jp = 0; jp < 4; jp++) {
          Al.w[jp] = pk2(vl[p] * s2l[2*jp], vl[p] * s2l[2*jp+1]);
          Ah.w[jp] = pk2(vh[p] * s2h[2*jp], vh[p] * s2h[2*jp+1]);
        }
        MFMA_V(Al, Ah, C1, p);
      }
    }
  }

  // V epilogue: gate + msg store, PLANE-MAJOR v channels: ch = 64 + p*32 + c
  // -> per-instruction stores are 16 lanes x 2B contiguous (32B chunks)
#pragma unroll
  for (int t = 0; t < 2; t++) {
#pragma unroll
    for (int r = 0; r < 4; r++) {
      int er = wv * 16 + quad * 4 + r + t * 64;
      int nid = idxL[er];
#pragma unroll
      for (int nt = 0; nt < 2; nt++) {
        int c = nt * 16 + ln;
        float g = gateR[t * 8 + nt * 4 + r];
#pragma unroll
        for (int p = 0; p < 3; p++) {
          float val = aV[t][p][nt][r] * g;
          if (use_msg) msg16[(size_t)(eb + er) * 160 + 64 + p * 32 + c] = f2b(val);
          else         atomicAdd(&v_n[nid * 96 + c * 3 + p], val);
        }
      }
    }
  }
}

// ---- gather: one wave per node; msg rows contiguous per node -------------
// dword d of row: d<32 -> s ch 2d,2d+1; d=32..79 -> v plane-major:
// p=(d-32)/16, c=2*((d-32)&15). lanes 0..63 read d=lane; lanes 0..15 read 64+lane.
__global__ __launch_bounds__(256) void gather_kernel(
    const int* __restrict__ off, const u32* __restrict__ msg,
    float* __restrict__ s_n, float* __restrict__ v_n) {
  int tid = threadIdx.x;
  int n = blockIdx.x * 4 + (tid >> 6);
  int lane = tid & 63;
  int beg = off[n], end = off[n + 1];
  float a0 = 0.f, a1 = 0.f, b0 = 0.f, b1 = 0.f;
#pragma unroll 2
  for (int k = beg; k < end; k++) {
    u32 w0 = msg[(size_t)k * 80 + lane];
    a0 += lo_f(w0); a1 += hi_f(w0);
    if (lane < 16) {
      u32 w1 = msg[(size_t)k * 80 + 64 + lane];
      b0 += lo_f(w1); b1 += hi_f(w1);
    }
  }
  if (lane < 32) {
    s_n[n * 64 + 2 * lane] = a0; s_n[n * 64 + 2 * lane + 1] = a1;
  } else if (lane < 48) {            // p=0, c=2*(lane-32)
    int c = 2 * (lane - 32);
    v_n[n * 96 + c * 3] = a0; v_n[n * 96 + (c + 1) * 3] = a1;
  } else {                           // p=1, c=2*(lane-48)
    int c = 2 * (lane - 48);
    v_n[n * 96 + c * 3 + 1] = a0; v_n[n * 96 + (c + 1) * 3 + 1] = a1;
  }
  if (lane < 16) {                   // p=2, c=2*lane
    int c = 2 * lane;
    v_n[n * 96 + c * 3 + 2] = b0; v_n[n * 96 + (c + 1) * 3 + 2] = b1;
  }
}

// ---- BN stats ------------------------------------------------------------
__global__ void stats_kernel(const float* __restrict__ s_n, const float* __restrict__ v_n,
                             float* __restrict__ stats) {
  int b = blockIdx.x, tid = threadIdx.x;
  int r0 = b * 50;
  int c = tid & 63, rg = tid >> 6;
  float s = 0.f, sq = 0.f;
  for (int r = r0 + rg; r < r0 + 50; r += 4) {
    float v = s_n[r * 64 + c];
    s += v; sq += v * v;
  }
  atomicAdd(&stats[c], s);
  atomicAdd(&stats[64 + c], sq);
  int c2 = tid & 31, rg2 = tid >> 5;
  float vn = 0.f;
  for (int r = r0 + rg2; r < r0 + 50; r += 8) {
    const float* vp = &v_n[r * 96 + c2 * 3];
    vn += vp[0] * vp[0] + vp[1] * vp[1] + vp[2] * vp[2];
  }
  atomicAdd(&stats[128 + c2], vn);
}

// ---- finalize ------------------------------------------------------------
__global__ void finalize_kernel(const float* __restrict__ s_n, const float* __restrict__ v_n,
                                const float* __restrict__ stats,
                                const float* __restrict__ x,
                                const float* __restrict__ bw_s, const float* __restrict__ bb_s,
                                const float* __restrict__ bw_v,
                                float* __restrict__ out) {
  int t = blockIdx.x * 256 + threadIdx.x;
  if (t >= NNODES * 160) return;
  int n = t / 160, j = t - n * 160;
  float xv = x[t];
  float r;
  if (j < 64) {
    float mu  = stats[j] * (1.f / NNODES);
    float var = stats[64 + j] * (1.f / NNODES) - mu * mu;
    var = fmaxf(var, 0.f);
    float v = s_n[n * 64 + j];
    r = (v - mu) * rsqrtf(var + 1e-5f) * bw_s[j] + bb_s[j];
  } else {
    int qq = j - 64;
    int c = qq / 3;
    float vn = stats[128 + c] * (1.f / (3.f * NNODES));
    float v = v_n[n * 96 + qq];
    r = v * rsqrtf(vn + 1e-5f) * bw_v[c];
  }
  out[t] = r + xv;
}

extern "C" void kernel_launch(void* const* d_in, const int* in_sizes, int n_in,
                              void* d_out, int out_size, void* d_ws, size_t ws_size,
                              hipStream_t stream) {
  const float* x      = (const float*)d_in[0];
  const float* ea     = (const float*)d_in[1];
  const float* W_ss   = (const float*)d_in[2];
  const float* W_vv_s = (const float*)d_in[3];
  const float* W_sv   = (const float*)d_in[4];
  const float* W_vs   = (const float*)d_in[5];
  const float* W_vv_v = (const float*)d_in[6];
  const float* bw_s   = (const float*)d_in[7];
  const float* bb_s   = (const float*)d_in[8];
  const float* bw_v   = (const float*)d_in[9];
  const int* eidx     = (const int*)d_in[10];
  float* out = (float*)d_out;

  float* ws    = (float*)d_ws;
  u16* WSp     = (u16*)d_ws;              // 122880 u16
  u16* WVp     = WSp + 122880;            // 40960 u16
  float* s_n   = ws + 81920;              // 640000
  float* v_n   = s_n + 640000;            // 960000
  float* stats = v_n + 960000;            // 160  (at 1681920)
  int* cnt     = (int*)(ws + 1682080);    // 10000 (contiguous after stats)
  int* off     = (int*)(ws + 1692080);    // 10001 (pad to 10004)
  int* cursor  = (int*)(ws + 1702084);    // 10000
  int* elist   = (int*)(ws + 1712084);    // 160000
  u32* msg     = (u32*)(ws + 1872084);    // 12,800,000 dwords = msg[e][160] bf16
  // total = 14,672,084 floats = 58,688,336 bytes

  int use_msg = (ws_size >= 58688336ULL) ? 1 : 0;

  if (use_msg) {
    // stats (160 f) and cnt (10000 i32) are adjacent: one memset covers both
    hipMemsetAsync(stats, 0, (160 + NNODES) * sizeof(float), stream);
    prep_kernel<<<625, 256, 0, stream>>>(W_ss, W_vv_s, W_sv, W_vs, W_vv_v,
                                         (u32*)WSp, (u32*)WVp, eidx, cnt, 1);
    scan_kernel<<<1, 1024, 0, stream>>>(cnt, off, cursor);
    fill_kernel<<<625, 256, 0, stream>>>(eidx, cursor, elist);
  } else {
    hipMemsetAsync(s_n, 0, 1600160 * sizeof(float), stream);
    prep_kernel<<<625, 256, 0, stream>>>(W_ss, W_vv_s, W_sv, W_vs, W_vv_v,
                                         (u32*)WSp, (u32*)WVp, eidx, cnt, 0);
  }
  edge_kernel<<<NEDGES / EB, 256, 0, stream>>>(x, ea, eidx, elist, WSp, WVp,
                                               s_n, v_n, (u16*)msg, use_msg);
  if (use_msg)
    gather_kernel<<<2500, 256, 0, stream>>>(off, msg, s_n, v_n);
  stats_kernel<<<200, 256, 0, stream>>>(s_n, v_n, stats);
  finalize_kernel<<<(NNODES * 160 + 255) / 256, 256, 0, stream>>>(
      s_n, v_n, stats, x, bw_s, bb_s, bw_v, out);
}

// Round 18
// 349.409 us; speedup vs baseline: 1.1576x; 1.0196x over previous
//
#include <hip/hip_runtime.h>
#include <hip/hip_bf16.h>

// NodeProcessor via MFMA. R18 = R17 (best: 356us; plane-major msg, node-
// sorted edges, (256,2) no-spill edge kernel) + STATS FUSED INTO GATHER:
// gather already holds each node's summed channels; a 160-float LDS block
// reduction + 160 global atomics/block replaces the stats kernel and its
// 12.8MB re-read of s_n/v_n (+1 launch hop). Edge kernel untouched.

#define NNODES 10000
#define NEDGES 160000
#define EB 128
#define FSTRD 65                    // fTd row stride in dwords (==1 mod 32)

typedef unsigned short u16;
typedef unsigned int u32;
typedef short short8 __attribute__((ext_vector_type(8)));
typedef float f32x4 __attribute__((ext_vector_type(4)));

__device__ __forceinline__ u16 f2b(float f) {  // RNE
  union { float f; u32 i; } v; v.f = f;
  u32 r = v.i + 0x7FFFu + ((v.i >> 16) & 1u);
  return (u16)(r >> 16);
}
__device__ __forceinline__ float lo_f(u32 d) {
  union { u32 i; float f; } v; v.i = d << 16; return v.f;
}
__device__ __forceinline__ float hi_f(u32 d) {
  union { u32 i; float f; } v; v.i = d & 0xFFFF0000u; return v.f;
}
__device__ __forceinline__ float qb(float f) {  // quantize to bf16 grid
  union { u32 i; float f; } v; v.i = ((u32)f2b(f)) << 16; return v.f;
}
__device__ __forceinline__ u32 pk2(float lo, float hi) {
  return __builtin_amdgcn_perm(__float_as_uint(hi), __float_as_uint(lo), 0x07060302u);
}
union frag_u { u32 w[4]; short8 s; };

#define INVF  0.02795084971874737f   // 1/sqrt(1280)
#define INV3  0.5773502691896258f    // 1/sqrt(3)
#define INV2  0.7071067811865476f    // 1/sqrt(2)

// ---- prep: pack weights (+ fused degree count; cnt pre-zeroed by memset) --
__global__ void prep_kernel(const float* __restrict__ W_ss, const float* __restrict__ W_vv_s,
                            const float* __restrict__ W_sv, const float* __restrict__ W_vs,
                            const float* __restrict__ W_vv_v,
                            u32* __restrict__ WSd, u32* __restrict__ WVd,
                            const int* __restrict__ eidx, int* __restrict__ cnt,
                            int do_count) {
  int t = blockIdx.x * 256 + threadIdx.x;
  if (do_count && t < NEDGES) atomicAdd(&cnt[eidx[t]], 1);
  if (t < 61440) {            // W_S dwords
    int d = t;
    int nt = d / 10240, r = d - nt * 10240;
    int kt = r >> 8, l = (r & 255) >> 2, jp = r & 3;
    int n = nt * 16 + (l & 15);
    int k0 = kt * 32 + ((l >> 4) << 3) + jp * 2;
    float f0, f1;
    f0 = (k0     < 1024) ? W_ss[k0 * 96 + n] * INVF       : W_vv_s[(k0 - 1024) * 96 + n] * (INVF * INV3);
    f1 = (k0 + 1 < 1024) ? W_ss[(k0 + 1) * 96 + n] * INVF : W_vv_s[(k0 - 1023) * 96 + n] * (INVF * INV3);
    WSd[d] = (u32)f2b(f0) | ((u32)f2b(f1) << 16);
  } else if (t < 81920) {     // W_V dwords
    int d = t - 61440;
    int nt = d / 10240, r = d - nt * 10240;
    int kt = r >> 8, l = (r & 255) >> 2, jp = r & 3;
    int n = nt * 16 + (l & 15);
    int k0 = kt * 32 + ((l >> 4) << 3) + jp * 2;
    float f[2];
#pragma unroll
    for (int jj = 0; jj < 2; jj++) {
      int k = k0 + jj;
      if (k < 512)       f[jj] = W_sv[k * 32 + n] * INVF;
      else if (k < 1024) f[jj] = W_vs[(k - 512) * 32 + n] * INVF;
      else               f[jj] = W_vv_v[(k - 1024) * 32 + n] * (INVF * INV2);
    }
    WVd[d] = (u32)f2b(f[0]) | ((u32)f2b(f[1]) << 16);
  }
}

__global__ void scan_kernel(const int* __restrict__ cnt, int* __restrict__ off,
                            int* __restrict__ cursor) {
  __shared__ int part[1024];
  int t = threadIdx.x;
  int local[10]; int s = 0;
  if (t < 1000) {
#pragma unroll
    for (int i = 0; i < 10; i++) { local[i] = cnt[t * 10 + i]; s += local[i]; }
  }
  part[t] = s; __syncthreads();
  for (int d = 1; d < 1024; d <<= 1) {
    int v = (t >= d) ? part[t - d] : 0; __syncthreads();
    part[t] += v; __syncthreads();
  }
  if (t < 1000) {
    int ex = (t == 0) ? 0 : part[t - 1];
#pragma unroll
    for (int i = 0; i < 10; i++) { off[t * 10 + i] = ex; cursor[t * 10 + i] = ex; ex += local[i]; }
  }
  if (t == 0) off[10000] = NEDGES;
}

__global__ void fill_kernel(const int* __restrict__ eidx, int* __restrict__ cursor,
                            int* __restrict__ elist) {
  int t = blockIdx.x * 256 + threadIdx.x;
  if (t < NEDGES) {
    int slot = atomicAdd(&cursor[eidx[t]], 1);
    elist[slot] = t;
  }
}

// ---- edge kernel (processes SLOT order when use_msg) — unchanged R17 -----
__global__ __launch_bounds__(256, 2) void edge_kernel(
    const float* __restrict__ x, const float* __restrict__ ea,
    const int* __restrict__ eidx, const int* __restrict__ elist,
    const u16* __restrict__ WSp, const u16* __restrict__ WVp,
    float* __restrict__ s_n, float* __restrict__ v_n,
    u16* __restrict__ msg16, int use_msg) {
  __shared__ int idxL[EB];
  __shared__ int eoL[EB];
  __shared__ u32 fTd[160 * FSTRD];  // [j][ep]: lo=edge ep, hi=edge ep+64 (x only)
  const int tid = threadIdx.x;
  const int eb = blockIdx.x * EB;

  if (tid < EB) {
    int eo = use_msg ? elist[eb + tid] : (eb + tid);
    eoL[tid] = eo;
    idxL[tid] = eidx[eo];
  }
  __syncthreads();
#pragma unroll 1
  for (int t = tid; t < 64 * 160; t += 256) {
    int ep2 = t / 160, j = t - ep2 * 160;
    float vlo = x[(size_t)idxL[ep2] * 160 + j];
    float vhi = x[(size_t)idxL[ep2 + 64] * 160 + j];
    fTd[j * FSTRD + ep2] = (u32)f2b(vlo) | ((u32)f2b(vhi) << 16);
  }
  __syncthreads();

  const int wv = tid >> 6, lane = tid & 63;
  const int ln = lane & 15, quad = lane >> 4;
  const int ep = wv * 16 + ln;
  const int qh = quad >> 1, bb = (quad & 1) * 8;

  // s2/v2 hoists: straight from global (this lane's 2 edges), bf16-quantized
  const float* eaL = ea + (size_t)eoL[ep] * 40;
  const float* eaH = ea + (size_t)eoL[ep + 64] * 40;
  float s2l[8], s2h[8], v2l[24], v2h[24];
  {
    float4 a0 = *(const float4*)(eaL + bb), a1 = *(const float4*)(eaL + bb + 4);
    float4 b0 = *(const float4*)(eaH + bb), b1 = *(const float4*)(eaH + bb + 4);
    s2l[0]=qb(a0.x); s2l[1]=qb(a0.y); s2l[2]=qb(a0.z); s2l[3]=qb(a0.w);
    s2l[4]=qb(a1.x); s2l[5]=qb(a1.y); s2l[6]=qb(a1.z); s2l[7]=qb(a1.w);
    s2h[0]=qb(b0.x); s2h[1]=qb(b0.y); s2h[2]=qb(b0.z); s2h[3]=qb(b0.w);
    s2h[4]=qb(b1.x); s2h[5]=qb(b1.y); s2h[6]=qb(b1.z); s2h[7]=qb(b1.w);
#pragma unroll
    for (int i = 0; i < 6; i++) {
      float4 va = *(const float4*)(eaL + 16 + 4 * i);
      float4 vb = *(const float4*)(eaH + 16 + 4 * i);
      v2l[4*i+0]=qb(va.x); v2l[4*i+1]=qb(va.y); v2l[4*i+2]=qb(va.z); v2l[4*i+3]=qb(va.w);
      v2h[4*i+0]=qb(vb.x); v2h[4*i+1]=qb(vb.y); v2h[4*i+2]=qb(vb.z); v2h[4*i+3]=qb(vb.w);
    }
  }

  const u16* WS_l = WSp + (size_t)lane * 8;
  const u16* WV_l = WVp + (size_t)lane * 8;

#define LOAD_BS(B, ktv) { _Pragma("unroll") \
  for (int nt = 0; nt < 6; nt++) B[nt].s = *(const short8*)(WS_l + (size_t)(ktv) * 512 + nt * 20480); }
#define LOAD_BV(C, ktv) { _Pragma("unroll") \
  for (int nt = 0; nt < 2; nt++) C[nt].s = *(const short8*)(WV_l + (size_t)(ktv) * 512 + nt * 20480); }
#define MFMA_S(Al, Ah, B) { _Pragma("unroll") \
  for (int nt = 0; nt < 6; nt++) { \
    aS[0][nt] = __builtin_amdgcn_mfma_f32_16x16x32_bf16(Al.s, B[nt].s, aS[0][nt], 0, 0, 0); \
    aS[1][nt] = __builtin_amdgcn_mfma_f32_16x16x32_bf16(Ah.s, B[nt].s, aS[1][nt], 0, 0, 0); } }
#define MFMA_V(Al, Ah, C, p) { \
    aV[0][p][0] = __builtin_amdgcn_mfma_f32_16x16x32_bf16(Al.s, C[0].s, aV[0][p][0], 0, 0, 0); \
    aV[0][p][1] = __builtin_amdgcn_mfma_f32_16x16x32_bf16(Al.s, C[1].s, aV[0][p][1], 0, 0, 0); \
    aV[1][p][0] = __builtin_amdgcn_mfma_f32_16x16x32_bf16(Ah.s, C[0].s, aV[1][p][0], 0, 0, 0); \
    aV[1][p][1] = __builtin_amdgcn_mfma_f32_16x16x32_bf16(Ah.s, C[1].s, aV[1][p][1], 0, 0, 0); }

  // ================= S phase =================
  f32x4 aS[2][6];
#pragma unroll
  for (int t = 0; t < 2; t++)
#pragma unroll
    for (int i = 0; i < 6; i++) aS[t][i] = (f32x4){0.f, 0.f, 0.f, 0.f};

  frag_u B0[6], B1[6];
  LOAD_BS(B0, 0);

#pragma unroll 1
  for (int c = 0; c < 16; c++) {      // region ss: kt 0..31
    int kt = 2 * c;
    u32 dA = fTd[(2 * kt + qh) * FSTRD + ep];
    u32 dB = fTd[(2 * kt + 2 + qh) * FSTRD + ep];
    LOAD_BS(B1, kt + 1);
    {
      frag_u Al, Ah;
      float slo = lo_f(dA), shi = hi_f(dA);
#pragma unroll
      for (int jp = 0; jp < 4; jp++) {
        Al.w[jp] = pk2(slo * s2l[2 * jp], slo * s2l[2 * jp + 1]);
        Ah.w[jp] = pk2(shi * s2h[2 * jp], shi * s2h[2 * jp + 1]);
      }
      MFMA_S(Al, Ah, B0);
    }
    LOAD_BS(B0, kt + 2);
    {
      frag_u Al, Ah;
      float slo = lo_f(dB), shi = hi_f(dB);
#pragma unroll
      for (int jp = 0; jp < 4; jp++) {
        Al.w[jp] = pk2(slo * s2l[2 * jp], slo * s2l[2 * jp + 1]);
        Ah.w[jp] = pk2(shi * s2h[2 * jp], shi * s2h[2 * jp + 1]);
      }
      MFMA_S(Al, Ah, B1);
    }
  }
#pragma unroll 1
  for (int c = 0; c < 4; c++) {       // region dot3: kt 32..39
    int kt = 32 + 2 * c;
    int r0 = (64 + (4 * (kt - 32) + quad) * 3) * FSTRD + ep;
    int r1 = r0 + 12 * FSTRD;
    u32 d0 = fTd[r0], d1 = fTd[r0 + FSTRD], d2 = fTd[r0 + 2 * FSTRD];
    u32 e0 = fTd[r1], e1 = fTd[r1 + FSTRD], e2 = fTd[r1 + 2 * FSTRD];
    LOAD_BS(B1, kt + 1);
    {
      frag_u Al, Ah;
      float x0 = lo_f(d0), x1 = lo_f(d1), x2 = lo_f(d2);
      float y0 = hi_f(d0), y1 = hi_f(d1), y2 = hi_f(d2);
#pragma unroll
      for (int jp = 0; jp < 4; jp++) {
        int j0 = 6 * jp, j1 = 6 * jp + 3;
        Al.w[jp] = pk2(x0*v2l[j0] + x1*v2l[j0+1] + x2*v2l[j0+2],
                       x0*v2l[j1] + x1*v2l[j1+1] + x2*v2l[j1+2]);
        Ah.w[jp] = pk2(y0*v2h[j0] + y1*v2h[j0+1] + y2*v2h[j0+2],
                       y0*v2h[j1] + y1*v2h[j1+1] + y2*v2h[j1+2]);
      }
      MFMA_S(Al, Ah, B0);
    }
    LOAD_BS(B0, kt + 2);
    {
      frag_u Al, Ah;
      float x0 = lo_f(e0), x1 = lo_f(e1), x2 = lo_f(e2);
      float y0 = hi_f(e0), y1 = hi_f(e1), y2 = hi_f(e2);
#pragma unroll
      for (int jp = 0; jp < 4; jp++) {
        int j0 = 6 * jp, j1 = 6 * jp + 3;
        Al.w[jp] = pk2(x0*v2l[j0] + x1*v2l[j0+1] + x2*v2l[j0+2],
                       x0*v2l[j1] + x1*v2l[j1+1] + x2*v2l[j1+2]);
        Ah.w[jp] = pk2(y0*v2h[j0] + y1*v2h[j0+1] + y2*v2h[j0+2],
                       y0*v2h[j1] + y1*v2h[j1+1] + y2*v2h[j1+2]);
      }
      MFMA_S(Al, Ah, B1);
    }
  }

  frag_u C0[2], C1[2];
  LOAD_BV(C0, 32);

  // S epilogue: silu -> msg store (or atomic fallback); gates -> regs
  float gateR[16];
#pragma unroll
  for (int t = 0; t < 2; t++) {
#pragma unroll
    for (int r = 0; r < 4; r++) {
      int er = wv * 16 + quad * 4 + r + t * 64;
      int nid = idxL[er];
#pragma unroll
      for (int nt = 0; nt < 6; nt++) {
        float v = aS[t][nt][r];
        float sg = 1.f / (1.f + __expf(-v));
        if (nt < 4) {
          if (use_msg) msg16[(size_t)(eb + er) * 160 + nt * 16 + ln] = f2b(v * sg);
          else         atomicAdd(&s_n[nid * 64 + nt * 16 + ln], v * sg);
        } else gateR[t * 8 + (nt - 4) * 4 + r] = sg;
      }
    }
  }

  // ================= V phase =================
  f32x4 aV[2][3][2];
#pragma unroll
  for (int t = 0; t < 2; t++)
#pragma unroll
    for (int p = 0; p < 3; p++)
#pragma unroll
      for (int nt = 0; nt < 2; nt++) aV[t][p][nt] = (f32x4){0.f, 0.f, 0.f, 0.f};

#pragma unroll 1
  for (int c = 0; c < 4; c++) {       // region cross: kt 32..39
    int kt = 32 + 2 * c;
    int r0 = (64 + (4 * (kt - 32) + quad) * 3) * FSTRD + ep;
    int r1 = r0 + 12 * FSTRD;
    u32 d0 = fTd[r0], d1 = fTd[r0 + FSTRD], d2 = fTd[r0 + 2 * FSTRD];
    u32 e0 = fTd[r1], e1 = fTd[r1 + FSTRD], e2 = fTd[r1 + 2 * FSTRD];
    LOAD_BV(C1, kt + 1);
    {
      float wl[3] = { lo_f(d0), lo_f(d1), lo_f(d2) };
      float wh[3] = { hi_f(d0), hi_f(d1), hi_f(d2) };
#pragma unroll
      for (int p = 0; p < 3; p++) {
        const int p1 = (p + 1) % 3, p2 = (p + 2) % 3;
        frag_u Al, Ah;
#pragma unroll
        for (int jp = 0; jp < 4; jp++) {
          int j0 = 6 * jp, j1 = 6 * jp + 3;
          Al.w[jp] = pk2(wl[p1]*v2l[j0+p2] - wl[p2]*v2l[j0+p1],
                         wl[p1]*v2l[j1+p2] - wl[p2]*v2l[j1+p1]);
          Ah.w[jp] = pk2(wh[p1]*v2h[j0+p2] - wh[p2]*v2h[j0+p1],
                         wh[p1]*v2h[j1+p2] - wh[p2]*v2h[j1+p1]);
        }
        MFMA_V(Al, Ah, C0, p);
      }
    }
    LOAD_BV(C0, (c < 3) ? (kt + 2) : 0);
    {
      float wl[3] = { lo_f(e0), lo_f(e1), lo_f(e2) };
      float wh[3] = { hi_f(e0), hi_f(e1), hi_f(e2) };
#pragma unroll
      for (int p = 0; p < 3; p++) {
        const int p1 = (p + 1) % 3, p2 = (p + 2) % 3;
        frag_u Al, Ah;
#pragma unroll
        for (int jp = 0; jp < 4; jp++) {
          int j0 = 6 * jp, j1 = 6 * jp + 3;
          Al.w[jp] = pk2(wl[p1]*v2l[j0+p2] - wl[p2]*v2l[j0+p1],
                         wl[p1]*v2l[j1+p2] - wl[p2]*v2l[j1+p1]);
          Ah.w[jp] = pk2(wh[p1]*v2h[j0+p2] - wh[p2]*v2h[j0+p1],
                         wh[p1]*v2h[j1+p2] - wh[p2]*v2h[j1+p1]);
        }
        MFMA_V(Al, Ah, C1, p);
      }
    }
  }
#pragma unroll 1
  for (int c = 0; c < 8; c++) {       // region sv: kt 0..15
    int kt = 2 * c;
    u32 dA = fTd[(4 * kt + quad) * FSTRD + ep];
    u32 dB = fTd[(4 * kt + 4 + quad) * FSTRD + ep];
    LOAD_BV(C1, kt + 1);
    {
      float slo = lo_f(dA), shi = hi_f(dA);
#pragma unroll
      for (int p = 0; p < 3; p++) {
        frag_u Al, Ah;
#pragma unroll
        for (int jp = 0; jp < 4; jp++) {
          Al.w[jp] = pk2(slo * v2l[(2*jp)*3 + p], slo * v2l[(2*jp+1)*3 + p]);
          Ah.w[jp] = pk2(shi * v2h[(2*jp)*3 + p], shi * v2h[(2*jp+1)*3 + p]);
        }
        MFMA_V(Al, Ah, C0, p);
      }
    }
    LOAD_BV(C0, kt + 2);
    {
      float slo = lo_f(dB), shi = hi_f(dB);
#pragma unroll
      for (int p = 0; p < 3; p++) {
        frag_u Al, Ah;
#pragma unroll
        for (int jp = 0; jp < 4; jp++) {
          Al.w[jp] = pk2(slo * v2l[(2*jp)*3 + p], slo * v2l[(2*jp+1)*3 + p]);
          Ah.w[jp] = pk2(shi * v2h[(2*jp)*3 + p], shi * v2h[(2*jp+1)*3 + p]);
        }
        MFMA_V(Al, Ah, C1, p);
      }
    }
  }
#pragma unroll 1
  for (int c = 0; c < 8; c++) {       // region vs: kt 16..31
    int kt = 16 + 2 * c;
    int r0 = (64 + (2 * (kt - 16) + qh) * 3) * FSTRD + ep;
    int r1 = r0 + 6 * FSTRD;
    u32 d0 = fTd[r0], d1 = fTd[r0 + FSTRD], d2 = fTd[r0 + 2 * FSTRD];
    u32 e0 = fTd[r1], e1 = fTd[r1 + FSTRD], e2 = fTd[r1 + 2 * FSTRD];
    LOAD_BV(C1, kt + 1);
    {
      float vl[3] = { lo_f(d0), lo_f(d1), lo_f(d2) };
      float vh[3] = { hi_f(d0), hi_f(d1), hi_f(d2) };
#pragma unroll
      for (int p = 0; p < 3; p++) {
        frag_u Al, Ah;
#pragma unroll
        for (int jp = 0; jp < 4; jp++) {
          Al.w[jp] = pk2(vl[p] * s2l[2*jp], vl[p] * s2l[2*jp+1]);
          Ah.w[jp] = pk2(vh[p] * s2h[2*jp], vh[p] * s2h[2*jp+1]);
        }
        MFMA_V(Al, Ah, C0, p);
      }
    }
    LOAD_BV(C0, (c < 7) ? (kt + 2) : 0);
    {
      float vl[3] = { lo_f(e0), lo_f(e1), lo_f(e2) };
      float vh[3] = { hi_f(e0), hi_f(e1), hi_f(e2) };
#pragma unroll
      for (int p = 0; p < 3; p++) {
        frag_u Al, Ah;
#pragma unroll
        for (int jp = 0; jp < 4; jp++) {
          Al.w[jp] = pk2(vl[p] * s2l[2*jp], vl[p] * s2l[2*jp+1]);
          Ah.w[jp] = pk2(vh[p] * s2h[2*jp], vh[p] * s2h[2*jp+1]);
        }
        MFMA_V(Al, Ah, C1, p);
      }
    }
  }

  // V epilogue: gate + msg store, PLANE-MAJOR v channels: ch = 64 + p*32 + c
#pragma unroll
  for (int t = 0; t < 2; t++) {
#pragma unroll
    for (int r = 0; r < 4; r++) {
      int er = wv * 16 + quad * 4 + r + t * 64;
      int nid = idxL[er];
#pragma unroll
      for (int nt = 0; nt < 2; nt++) {
        int c = nt * 16 + ln;
        float g = gateR[t * 8 + nt * 4 + r];
#pragma unroll
        for (int p = 0; p < 3; p++) {
          float val = aV[t][p][nt][r] * g;
          if (use_msg) msg16[(size_t)(eb + er) * 160 + 64 + p * 32 + c] = f2b(val);
          else         atomicAdd(&v_n[nid * 96 + c * 3 + p], val);
        }
      }
    }
  }
}

// ---- gather + fused BN stats: one wave per node --------------------------
// msg row dword d: d<32 -> s ch 2d,2d+1; d=32..79 -> v plane-major
// (p=(d-32)/16, c=2*((d-32)&15)). Per-block partials of {sum s, sum s^2,
// sum |v|^2} reduced in LDS, then 160 global atomics/block.
__global__ __launch_bounds__(256) void gather_kernel(
    const int* __restrict__ off, const u32* __restrict__ msg,
    float* __restrict__ s_n, float* __restrict__ v_n,
    float* __restrict__ stats) {
  __shared__ float red[160];   // [0..63] sum s, [64..127] sum s^2, [128..159] |v|^2
  int tid = threadIdx.x;
  if (tid < 160) red[tid] = 0.f;
  __syncthreads();

  int n = blockIdx.x * 4 + (tid >> 6);
  int lane = tid & 63;
  int beg = off[n], end = off[n + 1];
  float a0 = 0.f, a1 = 0.f, b0 = 0.f, b1 = 0.f;
#pragma unroll 2
  for (int k = beg; k < end; k++) {
    u32 w0 = msg[(size_t)k * 80 + lane];
    a0 += lo_f(w0); a1 += hi_f(w0);
    if (lane < 16) {
      u32 w1 = msg[(size_t)k * 80 + 64 + lane];
      b0 += lo_f(w1); b1 += hi_f(w1);
    }
  }
  if (lane < 32) {                   // s channels 2l, 2l+1
    int c = 2 * lane;
    s_n[n * 64 + c] = a0; s_n[n * 64 + c + 1] = a1;
    atomicAdd(&red[c], a0);          atomicAdd(&red[c + 1], a1);
    atomicAdd(&red[64 + c], a0 * a0); atomicAdd(&red[64 + c + 1], a1 * a1);
  } else if (lane < 48) {            // p=0, c=2*(lane-32)
    int c = 2 * (lane - 32);
    v_n[n * 96 + c * 3] = a0; v_n[n * 96 + (c + 1) * 3] = a1;
    atomicAdd(&red[128 + c], a0 * a0); atomicAdd(&red[128 + c + 1], a1 * a1);
  } else {                           // p=1, c=2*(lane-48)
    int c = 2 * (lane - 48);
    v_n[n * 96 + c * 3 + 1] = a0; v_n[n * 96 + (c + 1) * 3 + 1] = a1;
    atomicAdd(&red[128 + c], a0 * a0); atomicAdd(&red[128 + c + 1], a1 * a1);
  }
  if (lane < 16) {                   // p=2, c=2*lane
    int c = 2 * lane;
    v_n[n * 96 + c * 3 + 2] = b0; v_n[n * 96 + (c + 1) * 3 + 2] = b1;
    atomicAdd(&red[128 + c], b0 * b0); atomicAdd(&red[128 + c + 1], b1 * b1);
  }
  __syncthreads();
  if (tid < 160) atomicAdd(&stats[tid], red[tid]);
}

// ---- BN stats (fallback path only) ---------------------------------------
__global__ void stats_kernel(const float* __restrict__ s_n, const float* __restrict__ v_n,
                             float* __restrict__ stats) {
  int b = blockIdx.x, tid = threadIdx.x;
  int r0 = b * 50;
  int c = tid & 63, rg = tid >> 6;
  float s = 0.f, sq = 0.f;
  for (int r = r0 + rg; r < r0 + 50; r += 4) {
    float v = s_n[r * 64 + c];
    s += v; sq += v * v;
  }
  atomicAdd(&stats[c], s);
  atomicAdd(&stats[64 + c], sq);
  int c2 = tid & 31, rg2 = tid >> 5;
  float vn = 0.f;
  for (int r = r0 + rg2; r < r0 + 50; r += 8) {
    const float* vp = &v_n[r * 96 + c2 * 3];
    vn += vp[0] * vp[0] + vp[1] * vp[1] + vp[2] * vp[2];
  }
  atomicAdd(&stats[128 + c2], vn);
}

// ---- finalize ------------------------------------------------------------
__global__ void finalize_kernel(const float* __restrict__ s_n, const float* __restrict__ v_n,
                                const float* __restrict__ stats,
                                const float* __restrict__ x,
                                const float* __restrict__ bw_s, const float* __restrict__ bb_s,
                                const float* __restrict__ bw_v,
                                float* __restrict__ out) {
  int t = blockIdx.x * 256 + threadIdx.x;
  if (t >= NNODES * 160) return;
  int n = t / 160, j = t - n * 160;
  float xv = x[t];
  float r;
  if (j < 64) {
    float mu  = stats[j] * (1.f / NNODES);
    float var = stats[64 + j] * (1.f / NNODES) - mu * mu;
    var = fmaxf(var, 0.f);
    float v = s_n[n * 64 + j];
    r = (v - mu) * rsqrtf(var + 1e-5f) * bw_s[j] + bb_s[j];
  } else {
    int qq = j - 64;
    int c = qq / 3;
    float vn = stats[128 + c] * (1.f / (3.f * NNODES));
    float v = v_n[n * 96 + qq];
    r = v * rsqrtf(vn + 1e-5f) * bw_v[c];
  }
  out[t] = r + xv;
}

extern "C" void kernel_launch(void* const* d_in, const int* in_sizes, int n_in,
                              void* d_out, int out_size, void* d_ws, size_t ws_size,
                              hipStream_t stream) {
  const float* x      = (const float*)d_in[0];
  const float* ea     = (const float*)d_in[1];
  const float* W_ss   = (const float*)d_in[2];
  const float* W_vv_s = (const float*)d_in[3];
  const float* W_sv   = (const float*)d_in[4];
  const float* W_vs   = (const float*)d_in[5];
  const float* W_vv_v = (const float*)d_in[6];
  const float* bw_s   = (const float*)d_in[7];
  const float* bb_s   = (const float*)d_in[8];
  const float* bw_v   = (const float*)d_in[9];
  const int* eidx     = (const int*)d_in[10];
  float* out = (float*)d_out;

  float* ws    = (float*)d_ws;
  u16* WSp     = (u16*)d_ws;              // 122880 u16
  u16* WVp     = WSp + 122880;            // 40960 u16
  float* s_n   = ws + 81920;              // 640000
  float* v_n   = s_n + 640000;            // 960000
  float* stats = v_n + 960000;            // 160  (at 1681920)
  int* cnt     = (int*)(ws + 1682080);    // 10000 (contiguous after stats)
  int* off     = (int*)(ws + 1692080);    // 10001 (pad to 10004)
  int* cursor  = (int*)(ws + 1702084);    // 10000
  int* elist   = (int*)(ws + 1712084);    // 160000
  u32* msg     = (u32*)(ws + 1872084);    // 12,800,000 dwords = msg[e][160] bf16
  // total = 14,672,084 floats = 58,688,336 bytes

  int use_msg = (ws_size >= 58688336ULL) ? 1 : 0;

  if (use_msg) {
    // stats (160 f) and cnt (10000 i32) are adjacent: one memset covers both
    hipMemsetAsync(stats, 0, (160 + NNODES) * sizeof(float), stream);
    prep_kernel<<<625, 256, 0, stream>>>(W_ss, W_vv_s, W_sv, W_vs, W_vv_v,
                                         (u32*)WSp, (u32*)WVp, eidx, cnt, 1);
    scan_kernel<<<1, 1024, 0, stream>>>(cnt, off, cursor);
    fill_kernel<<<625, 256, 0, stream>>>(eidx, cursor, elist);
  } else {
    hipMemsetAsync(s_n, 0, 1600160 * sizeof(float), stream);
    prep_kernel<<<625, 256, 0, stream>>>(W_ss, W_vv_s, W_sv, W_vs, W_vv_v,
                                         (u32*)WSp, (u32*)WVp, eidx, cnt, 0);
  }
  edge_kernel<<<NEDGES / EB, 256, 0, stream>>>(x, ea, eidx, elist, WSp, WVp,
                                               s_n, v_n, (u16*)msg, use_msg);
  if (use_msg) {
    gather_kernel<<<2500, 256, 0, stream>>>(off, msg, s_n, v_n, stats);
  } else {
    stats_kernel<<<200, 256, 0, stream>>>(s_n, v_n, stats);
  }
  finalize_kernel<<<(NNODES * 160 + 255) / 256, 256, 0, stream>>>(
      s_n, v_n, stats, x, bw_s, bb_s, bw_v, out);
}